// Round 3
// baseline (250.414 us; speedup 1.0000x reference)
//
#include <hip/hip_runtime.h>
#include <stdint.h>

// CTC forward loss (blank=0, reduction='mean', raw logits as log-probs),
// linear-probability domain with PER-LANE pow2 scale tracking (int log2
// offset per lane, exact pow2 merge factors at the lane boundary shfl).
// One 64-lane wave per sample; lane l owns states 8l..8l+7 (512 states
// suffice: end = 2*target_len <= 510; deps only flow upward in s).
// Logits rows stream through an LDS ring via global_load_lds DMA.

constexpr int T_DIM = 1024;
constexpr int V_DIM = 1024;
constexpr int S_MAX = 256;
constexpr int RING  = 12;   // ring rows; waits hard-code 44/40 (counts exact)

constexpr float INV_LN2 = 1.44269504088896340736f;
constexpr float LN2     = 0.69314718055994530942f;

__device__ __forceinline__ float exp2_hw(float x) {
    float r; asm("v_exp_f32 %0, %1" : "=v"(r) : "v"(x)); return r;
}
__device__ __forceinline__ float log2_hw(float x) {
    float r; asm("v_log_f32 %0, %1" : "=v"(r) : "v"(x)); return r;
}
// exact 2^e for -126 <= e <= 127; 0 for e <= -127 (such contributions are
// negligible relative to the O(1)-normalized states they are added to)
__device__ __forceinline__ float pow2i(int e) {
    return (e > -127) ? __int_as_float((e + 127) << 23) : 0.f;
}
__device__ __forceinline__ void stage16(const float* g, float* lds_base) {
    __builtin_amdgcn_global_load_lds(
        (const __attribute__((address_space(1))) void*)(uintptr_t)g,
        (__attribute__((address_space(3))) void*)(uint32_t)(uintptr_t)lds_base,
        16, 0, 0);
}

__launch_bounds__(64, 1)
__global__ void ctc_alpha_lin(const float* __restrict__ logits,
                              const int* __restrict__ targets,
                              const int* __restrict__ tlen,
                              float* __restrict__ losses) {
    __shared__ float ring[RING][V_DIM];   // 48 KB
    __shared__ float afin[512];
    __shared__ int   aLsh[64];

    const int n = blockIdx.x;
    const int l = threadIdx.x;            // 0..63

    // odd states 8l+1,3,5,7 -> labels targets[4l+0..3]
    const int* tg = targets + n * S_MAX;
    const int c0 = tg[4 * l + 0], c1 = tg[4 * l + 1];
    const int c2 = tg[4 * l + 2], c3 = tg[4 * l + 3];
    const int pv = (l > 0) ? tg[4 * l - 1] : 0;
    const float am0 = (l > 0 && c0 != pv) ? 1.f : 0.f;  // skip-allow masks
    const float am1 = (c1 != c0) ? 1.f : 0.f;
    const float am2 = (c2 != c1) ? 1.f : 0.f;
    const float am3 = (c3 != c2) ? 1.f : 0.f;

    const float* gbase = logits + (size_t)n * T_DIM * V_DIM;

    // Drain the targets loads so the counted vmcnt waits below are exact.
    asm volatile("s_waitcnt vmcnt(0)" ::: "memory");

    for (int r = 0; r < RING; ++r) {      // 48 DMA loads outstanding
        const float* g = gbase + r * V_DIM + l * 4;
        stage16(g,       &ring[r][0]);
        stage16(g + 256, &ring[r][256]);
        stage16(g + 512, &ring[r][512]);
        stage16(g + 768, &ring[r][768]);
    }

    asm volatile("s_waitcnt vmcnt(44)" ::: "memory");   // row 0 resident
    float a0=0,a1=0,a2=0,a3=0,a4=0,a5=0,a6=0,a7=0;
    if (l == 0) {
        a0 = exp2_hw(ring[0][0]  * INV_LN2);
        a1 = exp2_hw(ring[0][c0] * INV_LN2);
    }
    int Lr = 0;                            // per-lane log2 scale

    asm volatile("s_waitcnt vmcnt(40)" ::: "memory");   // row 1 resident
    float pb = exp2_hw(ring[1][0]  * INV_LN2);
    float p0 = exp2_hw(ring[1][c0] * INV_LN2);
    float p1 = exp2_hw(ring[1][c1] * INV_LN2);
    float p2 = exp2_hw(ring[1][c2] * INV_LN2);
    float p3 = exp2_hw(ring[1][c3] * INV_LN2);

    int wr = 0, rd = 2;
    const float* gnext = gbase + RING * V_DIM;

    auto alpha_step = [&]() {
        float a7n = __shfl_up(a7, 1);           // alpha[8l-1], neighbor scale
        int   Ln  = __shfl_up(Lr, 1);
        if (l == 0) a7n = 0.f;                  // (lane0: Ln==Lr, harmless)
        const int   m  = (Lr > Ln) ? Lr : Ln;
        const float f1 = pow2i(Lr - m);         // own-scale adjust (<=1)
        const float f2 = pow2i(Ln - m);         // neighbor adjust (<=1)
        const float n7 = a7n * f2;
        a0*=f1; a1*=f1; a2*=f1; a3*=f1; a4*=f1; a5*=f1; a6*=f1; a7*=f1;
        Lr = m;
        const float t0 = (a0 + n7) * pb;
        const float t1 = fmaf(am0, n7, a1 + a0) * p0;
        const float t2 = (a2 + a1) * pb;
        const float t3 = fmaf(am1, a1, a3 + a2) * p1;
        const float t4 = (a4 + a3) * pb;
        const float t5 = fmaf(am2, a3, a5 + a4) * p2;
        const float t6 = (a6 + a5) * pb;
        const float t7 = fmaf(am3, a5, a7 + a6) * p3;
        a0=t0; a1=t1; a2=t2; a3=t3; a4=t4; a5=t5; a6=t6; a7=t7;
    };
    auto renorm = [&]() {                        // per-lane, no cross-lane ops
        const float mx = fmaxf(fmaxf(fmaxf(a0,a1), fmaxf(a2,a3)),
                               fmaxf(fmaxf(a4,a5), fmaxf(a6,a7)));
        const int eu = ((__float_as_int(mx) >> 23) & 0xFF) - 127;
        const float sc = pow2i(-eu);             // eu>=-127 -> -eu<=127, valid
        a0*=sc; a1*=sc; a2*=sc; a3*=sc; a4*=sc; a5*=sc; a6*=sc; a7*=sc;
        Lr += eu;
    };

    for (int t = 1; t <= T_DIM - RING; ++t) {
        {   // stage row t+RING-1 into slot (t-1)%RING
            const float* g = gnext + l * 4;
            stage16(g,       &ring[wr][0]);
            stage16(g + 256, &ring[wr][256]);
            stage16(g + 512, &ring[wr][512]);
            stage16(g + 768, &ring[wr][768]);
            gnext += V_DIM;
            if (++wr == RING) wr = 0;
        }
        asm volatile("s_waitcnt vmcnt(40)" ::: "memory");  // row t+1 resident
        const float* rp = ring[rd];
        const float lb = rp[0], w0 = rp[c0], w1 = rp[c1], w2 = rp[c2], w3 = rp[c3];
        if (++rd == RING) rd = 0;

        alpha_step();                       // uses row-t p's; hides ds latency

        pb = exp2_hw(lb * INV_LN2);
        p0 = exp2_hw(w0 * INV_LN2);
        p1 = exp2_hw(w1 * INV_LN2);
        p2 = exp2_hw(w2 * INV_LN2);
        p3 = exp2_hw(w3 * INV_LN2);

        if ((t & 7) == 0) renorm();
    }

    asm volatile("s_waitcnt vmcnt(0)" ::: "memory");       // all rows resident
    for (int t = T_DIM - RING + 1; t < T_DIM; ++t) {
        const bool more = (t + 1 < T_DIM);
        float lb = 0, w0 = 0, w1 = 0, w2 = 0, w3 = 0;
        if (more) {
            const float* rp = ring[rd];
            lb = rp[0]; w0 = rp[c0]; w1 = rp[c1]; w2 = rp[c2]; w3 = rp[c3];
            if (++rd == RING) rd = 0;
        }
        alpha_step();
        if (more) {
            pb = exp2_hw(lb * INV_LN2);
            p0 = exp2_hw(w0 * INV_LN2);
            p1 = exp2_hw(w1 * INV_LN2);
            p2 = exp2_hw(w2 * INV_LN2);
            p3 = exp2_hw(w3 * INV_LN2);
        }
        if ((t & 7) == 0) renorm();
    }

    afin[8*l+0]=a0; afin[8*l+1]=a1; afin[8*l+2]=a2; afin[8*l+3]=a3;
    afin[8*l+4]=a4; afin[8*l+5]=a5; afin[8*l+6]=a6; afin[8*l+7]=a7;
    aLsh[l] = Lr;
    asm volatile("s_waitcnt lgkmcnt(0)" ::: "memory");  // single wave: no barrier
    if (l == 0) {
        const int tl_ = tlen[n];
        const int e  = 2 * tl_;                          // 256..510
        const float v1 = afin[e];     const int L1 = aLsh[e >> 3];
        const float v0 = afin[e - 1]; const int L0 = aLsh[(e - 1) >> 3];
        const int   Lm = (L1 > L0) ? L1 : L0;
        const float s  = v1 * pow2i(L1 - Lm) + v0 * pow2i(L0 - Lm);
        const float ll = LN2 * (log2_hw(s) + (float)Lm); // natural-log ll
        losses[n] = -ll / (float)tl_;
    }
}

__global__ void reduce_mean_kernel(const float* __restrict__ losses,
                                   float* __restrict__ out, int N) {
    float v = 0.0f;
    for (int i = threadIdx.x; i < N; i += 64) v += losses[i];
    #pragma unroll
    for (int off = 32; off > 0; off >>= 1) v += __shfl_down(v, off);
    if (threadIdx.x == 0) out[0] = v / (float)N;
}

extern "C" void kernel_launch(void* const* d_in, const int* in_sizes, int n_in,
                              void* d_out, int out_size, void* d_ws, size_t ws_size,
                              hipStream_t stream) {
    const float* logits  = (const float*)d_in[0];
    const int*   targets = (const int*)d_in[1];
    // d_in[2] = input_lengths (all == T, unused)
    const int*   tlen    = (const int*)d_in[3];
    const int N = in_sizes[3];

    float* losses = (float*)d_ws;   // N floats of scratch

    ctc_alpha_lin<<<N, 64, 0, stream>>>(logits, targets, tlen, losses);
    reduce_mean_kernel<<<1, 64, 0, stream>>>(losses, (float*)d_out, N);
}